// Round 24
// baseline (457.853 us; speedup 1.0000x reference)
//
#include <hip/hip_runtime.h>
#include <math.h>

#define BQ 1024
#define FDIM 128
#define DDIM 256
#define DIDIM 512
#define NTOT 100000
#define NP 100096            // padded to multiple of 128
#define NCVT 12512           // cand-convert blocks (NP*32/256)
#define NPACK 1024           // final-MLP weight-pack columns (256+512+256)
#define CTX 96
#define CAP 8192
#define MSUB 12288
#define RSUB 48
#define LBUF 1280            // per-block LDS survivor buffer (~150 sigma headroom)
#define CSTR 16              // cnt stride (1 cache line per row)

// split-f16 pack offsets for final-MLP weights (f16 units)
#define WT2OFF 0
#define WP1OFF (256*1536)
#define WP2OFF (WP1OFF + 512*768)

typedef _Float16 f16x8 __attribute__((ext_vector_type(8)));
typedef _Float16 f16x4 __attribute__((ext_vector_type(4)));
typedef float f32x4 __attribute__((ext_vector_type(4)));

// ---------- K0: fused prep: cand convert || Wf/WfT1 rows || bf || final-W packs ----------
__global__ __launch_bounds__(256) void k_prep(
    const float* __restrict__ cand, _Float16* __restrict__ c2,
    const float* __restrict__ Wlin, const float* __restrict__ blin,
    const float* __restrict__ WK, const float* __restrict__ bK,
    const float* __restrict__ WT1,
    const float* __restrict__ WT2, const float* __restrict__ WP1,
    const float* __restrict__ WP2,
    float* __restrict__ Wf, float* __restrict__ bf, float* __restrict__ WfT1,
    _Float16* __restrict__ Wfin)
{
    int blk = blockIdx.x, tid = threadIdx.x;
    if (blk < NCVT) {
        int t = blk*256 + tid;
        int row = t >> 5;
        int c4 = (t & 31) * 4;
        float4 v = {0.f, 0.f, 0.f, 0.f};
        if (row < NTOT) v = *(const float4*)(cand + (size_t)row*FDIM + c4);
        float vv[4] = {v.x, v.y, v.z, v.w};
        f16x4 h, hs, l;
        #pragma unroll
        for (int q = 0; q < 4; ++q) {
            _Float16 hq = (_Float16)vv[q];
            float hf = (float)hq;
            h[q]  = hq;
            hs[q] = (_Float16)(hf * 0.015625f);
            l[q]  = (_Float16)((vv[q] - hf) * 64.f);
        }
        size_t b = (size_t)row*384 + c4;
        *(f16x4*)(c2 + b)       = h;
        *(f16x4*)(c2 + b + 128) = hs;
        *(f16x4*)(c2 + b + 256) = l;
        return;
    }
    int i = blk - NCVT;
    if (i > FDIM) {
        // final-MLP weight pack: B-convention [h, l, hs]
        int c = i - FDIM - 1;
        const float* W; int K, N, cl; size_t base;
        if (c < 256)      { W = WT2; K = 512; N = 256; cl = c;     base = (size_t)WT2OFF + (size_t)c*1536; }
        else if (c < 768) { W = WP1; K = 256; N = 512; cl = c-256; base = (size_t)WP1OFF + (size_t)(c-256)*768; }
        else              { W = WP2; K = 512; N = 256; cl = c-768; base = (size_t)WP2OFF + (size_t)(c-768)*1536; }
        for (int k = tid; k < K; k += 256) {
            float w = W[(size_t)k*N + cl];
            _Float16 h = (_Float16)w;
            float hf = (float)h;
            Wfin[base + k]       = h;
            Wfin[base + K + k]   = (_Float16)((w - hf) * 64.f);
            Wfin[base + 2*K + k] = (_Float16)(hf * 0.015625f);
        }
        return;
    }
    __shared__ float red[256];
    int j = tid;
    if (i < FDIM) {
        float acc = 0.f;
        for (int l = 0; l < DDIM; ++l) acc += Wlin[i*DDIM + l] * WK[l*DDIM + j];
        Wf[i*DDIM + j] = acc;
        red[j] = acc;
        __syncthreads();
        float a0 = 0.f, a1 = 0.f;
        for (int l = 0; l < DDIM; ++l) {
            float w = red[l];
            a0 += w * WT1[(size_t)l*DIDIM + j];
            a1 += w * WT1[(size_t)l*DIDIM + j + 256];
        }
        WfT1[(size_t)i*DIDIM + j] = a0;
        WfT1[(size_t)i*DIDIM + j + 256] = a1;
    } else {
        float acc = bK[j];
        for (int l = 0; l < DDIM; ++l) acc += blin[l] * WK[l*DDIM + j];
        bf[j] = acc;
        red[j] = acc*acc; __syncthreads();
        for (int s2 = 128; s2 > 0; s2 >>= 1) { if (j < s2) red[j] += red[j+s2]; __syncthreads(); }
        if (j == 0) bf[256] = red[0];
    }
}

// ---------- K1: qenc blocks || weight-pack blocks ----------
__global__ __launch_bounds__(256) void k_prep2(
    const float* __restrict__ x, const float* __restrict__ Wlin,
    const float* __restrict__ blin, const float* __restrict__ Wf,
    const float* __restrict__ bf, const float* __restrict__ WfT1,
    const float* __restrict__ bT1,
    float* __restrict__ xenc, float* __restrict__ kp,
    _Float16* __restrict__ kp2, float* __restrict__ xP,
    _Float16* __restrict__ Wsp)
{
    __shared__ float xs[FDIM];
    __shared__ float ks[DDIM];
    int blk = blockIdx.x, tid = threadIdx.x;
    if (blk >= BQ) {
        int jj = (blk - BQ)*2 + (tid >> 7);
        int l = tid & 127;
        float w = (jj < DDIM) ? Wf[l*DDIM + jj] : WfT1[(size_t)l*DIDIM + (jj - DDIM)];
        _Float16 h = (_Float16)w;
        float hf = (float)h;
        Wsp[(size_t)jj*384 + l]       = h;
        Wsp[(size_t)jj*384 + 128 + l] = (_Float16)((w - hf) * 64.f);
        Wsp[(size_t)jj*384 + 256 + l] = (_Float16)(hf * 0.015625f);
        return;
    }
    int b = blk, j = tid;
    if (j < FDIM) xs[j] = x[(size_t)b*FDIM + j];
    __syncthreads();
    float a0 = blin[j], a1 = bf[j];
    for (int l = 0; l < FDIM; ++l) {
        float xv = xs[l];
        a0 += xv * Wlin[l*DDIM + j];
        a1 += xv * Wf[l*DDIM + j];
    }
    xenc[(size_t)b*DDIM + j] = a0;
    ks[j] = a1;
    float p0 = bT1[j], p1 = bT1[j + 256];
    for (int l = 0; l < FDIM; ++l) {
        float xv = xs[l];
        p0 += xv * WfT1[(size_t)l*DIDIM + j];
        p1 += xv * WfT1[(size_t)l*DIDIM + j + 256];
    }
    xP[(size_t)b*DIDIM + j] = p0;
    xP[(size_t)b*DIDIM + j + 256] = p1;
    __syncthreads();
    if (j < FDIM) {
        float a = 0.f;
        for (int d = 0; d < DDIM; ++d) a += Wf[j*DDIM + d] * ks[d];
        kp[(size_t)b*FDIM + j] = a;
        _Float16 h = (_Float16)a;
        float hf = (float)h;
        kp2[(size_t)b*384 + j]       = h;
        kp2[(size_t)b*384 + 128 + j] = (_Float16)((a - hf) * 64.f);
        kp2[(size_t)b*384 + 256 + j] = (_Float16)(hf * 0.015625f);
    }
}

// ---------- kinorm GEMM (round-16 2D version, 32 KB LDS) ----------
__global__ __launch_bounds__(256) void k_cnorm(
    const _Float16* __restrict__ A, const _Float16* __restrict__ B,
    float* __restrict__ knp, const float* __restrict__ bf)
{
    __shared__ __align__(16) _Float16 As[128*64];
    __shared__ __align__(16) _Float16 Bs[128*64];
    int tid = threadIdx.x;
    int lane = tid & 63, wv = tid >> 6;
    int wm = wv >> 1, wn = wv & 1;
    int bn = blockIdx.x * 128;
    int bm = blockIdx.y * 128;
    f32x4 acc[4][4] = {};
    const size_t baseA = (size_t)bm * 384;
    const size_t baseB = (size_t)bn * 384;
    for (int kt = 0; kt < 6; ++kt) {
        #pragma unroll
        for (int r = 0; r < 4; ++r) {
            int w = wv*4 + r;
            int s = w*64 + lane;
            int rl = s & 15;
            int q  = (s >> 4) & 3;
            int kk2= (s >> 6) & 1;
            int ii = (s >> 7) & 3;
            int wq = (s >> 9) & 1;
            size_t goff = (size_t)(wq*64 + ii*16 + rl)*384 + kt*64 + (kk2*4 + q)*8;
            __builtin_amdgcn_global_load_lds(
                (const __attribute__((address_space(1))) void*)(A + baseA + goff),
                (__attribute__((address_space(3))) void*)(As + w*512), 16, 0, 0);
            __builtin_amdgcn_global_load_lds(
                (const __attribute__((address_space(1))) void*)(B + baseB + goff),
                (__attribute__((address_space(3))) void*)(Bs + w*512), 16, 0, 0);
        }
        __syncthreads();
        #pragma unroll
        for (int kk = 0; kk < 2; ++kk) {
            f16x8 af[4], bfr[4];
            #pragma unroll
            for (int i = 0; i < 4; ++i)
                af[i] = *(const f16x8*)&As[((wm*8 + i*2 + kk)*64 + (lane>>4)*16 + (lane&15))*8];
            #pragma unroll
            for (int j = 0; j < 4; ++j)
                bfr[j] = *(const f16x8*)&Bs[((wn*8 + j*2 + kk)*64 + (lane>>4)*16 + (lane&15))*8];
            #pragma unroll
            for (int i = 0; i < 4; ++i)
                #pragma unroll
                for (int j = 0; j < 4; ++j)
                    acc[i][j] = __builtin_amdgcn_mfma_f32_16x16x32_f16(af[i], bfr[j], acc[i][j], 0, 0, 0);
        }
        __syncthreads();
    }
    float bfv[4];
    #pragma unroll
    for (int j = 0; j < 4; ++j) bfv[j] = bf[bn + wn*64 + j*16 + (lane&15)];
    int bnt = bn >> 7;
    #pragma unroll
    for (int i = 0; i < 4; ++i) {
        #pragma unroll
        for (int rg = 0; rg < 4; ++rg) {
            float s = 0.f;
            #pragma unroll
            for (int j = 0; j < 4; ++j) {
                float q = acc[i][j][rg];
                s += q * (q + 2.f*bfv[j]);
            }
            s += __shfl_xor(s, 1, 64);
            s += __shfl_xor(s, 2, 64);
            s += __shfl_xor(s, 4, 64);
            s += __shfl_xor(s, 8, 64);
            if ((lane & 15) == 0) {
                int row = bm + wm*64 + i*16 + (lane>>4)*4 + rg;
                knp[(size_t)(bnt*2 + wn)*NP + row] = s;
            }
        }
    }
}

// ---------- finalize kinorm ----------
__global__ __launch_bounds__(256) void k_norm_fin(
    const float* __restrict__ knp, const float* __restrict__ bf, float* __restrict__ kinorm)
{
    int n = blockIdx.x*256 + threadIdx.x;
    kinorm[n] = (n < NTOT)
        ? bf[256] + knp[n] + knp[(size_t)NP + n] + knp[(size_t)2*NP + n] + knp[(size_t)3*NP + n]
        : INFINITY;
}

// ---------- mini score GEMM (K=128, hi-slot only) over first MSUB candidates ----------
__global__ __launch_bounds__(256) void k_mini(
    const _Float16* __restrict__ kp2, const _Float16* __restrict__ cand2,
    const float* __restrict__ kinorm, _Float16* __restrict__ msb)
{
    __shared__ __align__(16) _Float16 As[128*64];
    __shared__ __align__(16) _Float16 Bs[128*64];
    int tid = threadIdx.x;
    int lane = tid & 63, wv = tid >> 6;
    int wm = wv >> 1, wn = wv & 1;
    int bm = blockIdx.x * 128;
    int bn = blockIdx.y * 128;
    f32x4 acc[4][4] = {};
    const size_t baseA = (size_t)bm * 384;
    const size_t baseB = (size_t)bn * 384;
    for (int kt = 0; kt < 2; ++kt) {
        #pragma unroll
        for (int r = 0; r < 4; ++r) {
            int w = wv*4 + r;
            int s = w*64 + lane;
            int rl = s & 15;
            int q  = (s >> 4) & 3;
            int kk2= (s >> 6) & 1;
            int ii = (s >> 7) & 3;
            int wq = (s >> 9) & 1;
            size_t goff = (size_t)(wq*64 + ii*16 + rl)*384 + kt*64 + (kk2*4 + q)*8;
            __builtin_amdgcn_global_load_lds(
                (const __attribute__((address_space(1))) void*)(kp2 + baseA + goff),
                (__attribute__((address_space(3))) void*)(As + w*512), 16, 0, 0);
            __builtin_amdgcn_global_load_lds(
                (const __attribute__((address_space(1))) void*)(cand2 + baseB + goff),
                (__attribute__((address_space(3))) void*)(Bs + w*512), 16, 0, 0);
        }
        __syncthreads();
        #pragma unroll
        for (int kk = 0; kk < 2; ++kk) {
            f16x8 af[4], bfr[4];
            #pragma unroll
            for (int i = 0; i < 4; ++i)
                af[i] = *(const f16x8*)&As[((wm*8 + i*2 + kk)*64 + (lane>>4)*16 + (lane&15))*8];
            #pragma unroll
            for (int j = 0; j < 4; ++j)
                bfr[j] = *(const f16x8*)&Bs[((wn*8 + j*2 + kk)*64 + (lane>>4)*16 + (lane&15))*8];
            #pragma unroll
            for (int i = 0; i < 4; ++i)
                #pragma unroll
                for (int j = 0; j < 4; ++j)
                    acc[i][j] = __builtin_amdgcn_mfma_f32_16x16x32_f16(af[i], bfr[j], acc[i][j], 0, 0, 0);
        }
        __syncthreads();
    }
    #pragma unroll
    for (int i = 0; i < 4; ++i) {
        int m = bm + wm*64 + i*16 + (lane>>4)*4;
        #pragma unroll
        for (int j = 0; j < 4; ++j) {
            int nl = bn + wn*64 + j*16 + (lane&15);
            float kn = kinorm[nl];
            #pragma unroll
            for (int rg = 0; rg < 4; ++rg)
                msb[(size_t)(m + rg)*MSUB + nl] = (_Float16)fmaxf(kn - 2.f*acc[i][j][rg], 0.f);
        }
    }
}

// ---------- per-row subsample threshold + zero cnt ----------
__global__ __launch_bounds__(256) void k_subT(
    const unsigned short* __restrict__ msb, int* __restrict__ Tq, int* __restrict__ cnt)
{
    __shared__ unsigned h[1024];
    __shared__ unsigned pr[256];
    __shared__ unsigned h2[64];
    __shared__ int tstar;
    __shared__ unsigned cbel;
    int b = blockIdx.x, tid = threadIdx.x;
    if (tid == 0) cnt[b*CSTR] = 0;
    #pragma unroll
    for (int i = 0; i < 4; ++i) h[tid + i*256] = 0;
    if (tid == 0) tstar = 1023;
    if (tid < 64) h2[tid] = 0;
    __syncthreads();
    const unsigned short* row = msb + (size_t)b*MSUB;
    for (int base = 0; base < MSUB; base += 2048) {
        uint4 u = *(const uint4*)(row + base + tid*8);
        atomicAdd(&h[(u.x & 0xffffu) >> 6], 1u);
        atomicAdd(&h[(u.x >> 16) >> 6], 1u);
        atomicAdd(&h[(u.y & 0xffffu) >> 6], 1u);
        atomicAdd(&h[(u.y >> 16) >> 6], 1u);
        atomicAdd(&h[(u.z & 0xffffu) >> 6], 1u);
        atomicAdd(&h[(u.z >> 16) >> 6], 1u);
        atomicAdd(&h[(u.w & 0xffffu) >> 6], 1u);
        atomicAdd(&h[(u.w >> 16) >> 6], 1u);
    }
    __syncthreads();
    unsigned s0 = h[tid*4], s1 = h[tid*4+1], s2 = h[tid*4+2], s3 = h[tid*4+3];
    unsigned tot = s0 + s1 + s2 + s3;
    pr[tid] = tot;
    __syncthreads();
    for (int off = 1; off < 256; off <<= 1) {
        unsigned t2 = (tid >= off) ? pr[tid - off] : 0;
        __syncthreads();
        pr[tid] += t2;
        __syncthreads();
    }
    unsigned c = pr[tid] - tot;
    int found = -1;
    c += s0; if (c >= RSUB) found = tid*4;
    if (found < 0) { c += s1; if (c >= RSUB) found = tid*4+1; }
    if (found < 0) { c += s2; if (c >= RSUB) found = tid*4+2; }
    if (found < 0) { c += s3; if (c >= RSUB) found = tid*4+3; }
    if (found >= 0) atomicMin(&tstar, found);
    __syncthreads();
    if (tid == (tstar >> 2)) {
        unsigned below = pr[tid] - tot;
        int pos = tstar & 3;
        if (pos > 0) below += s0;
        if (pos > 1) below += s1;
        if (pos > 2) below += s2;
        cbel = below;
    }
    __syncthreads();
    int ts = tstar;
    for (int base = 0; base < MSUB; base += 2048) {
        uint4 u = *(const uint4*)(row + base + tid*8);
        unsigned e[8] = { u.x & 0xffffu, u.x >> 16, u.y & 0xffffu, u.y >> 16,
                          u.z & 0xffffu, u.z >> 16, u.w & 0xffffu, u.w >> 16 };
        #pragma unroll
        for (int q = 0; q < 8; ++q)
            if ((int)(e[q] >> 6) == ts) atomicAdd(&h2[e[q] & 63], 1u);
    }
    __syncthreads();
    if (tid == 0) {
        unsigned cum = cbel; int code = 63;
        for (int i = 0; i < 64; ++i) { cum += h2[i]; if (cum >= RSUB) { code = i; break; } }
        Tq[b] = (ts << 6) + code;
    }
}

// ---------- main score GEMM (LDS-staged kinorm/Tq epilogue) ----------
__global__ __launch_bounds__(256) void k_dist_mfma(
    const _Float16* __restrict__ kp2, const _Float16* __restrict__ cand2,
    const float* __restrict__ kinorm, const int* __restrict__ Tq,
    int* __restrict__ cnt, int* __restrict__ candI)
{
    __shared__ __align__(16) _Float16 As[128*64];
    __shared__ __align__(16) _Float16 Bs[128*64];
    __shared__ int lcnt;
    __shared__ unsigned lbuf[LBUF];
    __shared__ float kns[128];
    __shared__ int tqss[128];
    int tid = threadIdx.x;
    int lane = tid & 63, wv = tid >> 6;
    int wm = wv >> 1, wn = wv & 1;
    int r0 = blockIdx.x & 7, u0 = blockIdx.x >> 3;
    int pq = r0*782 + u0;
    int bm = (pq & 7) * 128;
    int bn = (pq >> 3) * 128;
    if (tid == 0) lcnt = 0;
    if (tid < 128) { kns[tid] = kinorm[bn + tid]; tqss[tid] = Tq[bm + tid]; }
    f32x4 acc[4][4] = {};
    const size_t baseA = (size_t)bm * 384;
    const size_t baseB = (size_t)bn * 384;
    for (int kt = 0; kt < 2; ++kt) {
        #pragma unroll
        for (int r = 0; r < 4; ++r) {
            int w = wv*4 + r;
            int s = w*64 + lane;
            int rl = s & 15;
            int q  = (s >> 4) & 3;
            int kk2= (s >> 6) & 1;
            int ii = (s >> 7) & 3;
            int wq = (s >> 9) & 1;
            size_t goff = (size_t)(wq*64 + ii*16 + rl)*384 + kt*64 + (kk2*4 + q)*8;
            __builtin_amdgcn_global_load_lds(
                (const __attribute__((address_space(1))) void*)(kp2 + baseA + goff),
                (__attribute__((address_space(3))) void*)(As + w*512), 16, 0, 0);
            __builtin_amdgcn_global_load_lds(
                (const __attribute__((address_space(1))) void*)(cand2 + baseB + goff),
                (__attribute__((address_space(3))) void*)(Bs + w*512), 16, 0, 0);
        }
        __syncthreads();
        #pragma unroll
        for (int kk = 0; kk < 2; ++kk) {
            f16x8 af[4], bfr[4];
            #pragma unroll
            for (int i = 0; i < 4; ++i)
                af[i] = *(const f16x8*)&As[((wm*8 + i*2 + kk)*64 + (lane>>4)*16 + (lane&15))*8];
            #pragma unroll
            for (int j = 0; j < 4; ++j)
                bfr[j] = *(const f16x8*)&Bs[((wn*8 + j*2 + kk)*64 + (lane>>4)*16 + (lane&15))*8];
            #pragma unroll
            for (int i = 0; i < 4; ++i)
                #pragma unroll
                for (int j = 0; j < 4; ++j)
                    acc[i][j] = __builtin_amdgcn_mfma_f32_16x16x32_f16(af[i], bfr[j], acc[i][j], 0, 0, 0);
        }
        __syncthreads();
    }
    #pragma unroll
    for (int i = 0; i < 4; ++i) {
        int m0 = bm + wm*64 + i*16 + (lane>>4)*4;
        int lrow = wm*64 + i*16 + (lane>>4)*4;
        int tqs[4];
        #pragma unroll
        for (int rg = 0; rg < 4; ++rg) tqs[rg] = tqss[lrow + rg];
        #pragma unroll
        for (int j = 0; j < 4; ++j) {
            int lcol = wn*64 + j*16 + (lane&15);
            int nl = bn + lcol;
            float kn = kns[lcol];
            #pragma unroll
            for (int rg = 0; rg < 4; ++rg) {
                float sc = fmaxf(kn - 2.f*acc[i][j][rg], 0.f);
                _Float16 k16 = (_Float16)sc;
                unsigned short kb;
                __builtin_memcpy(&kb, &k16, 2);
                if (kb <= (unsigned short)tqs[rg]) {
                    int p = atomicAdd(&lcnt, 1);
                    if (p < LBUF) lbuf[p] = ((unsigned)(m0 + rg) << 17) | (unsigned)nl;
                    else {
                        int pp = atomicAdd(&cnt[(m0 + rg)*CSTR], 1);
                        if (pp < CAP) candI[(size_t)(m0 + rg)*CAP + pp] = nl;
                    }
                }
            }
        }
    }
    __syncthreads();
    int c = lcnt < LBUF ? lcnt : LBUF;
    for (int i2 = tid; i2 < c; i2 += 256) {
        unsigned pk = lbuf[i2];
        int row = pk >> 17, col = (int)(pk & 0x1ffffu);
        int pp = atomicAdd(&cnt[row*CSTR], 1);
        if (pp < CAP) candI[(size_t)row*CAP + pp] = col;
    }
}

// ---------- fp32 row score helper ----------
__device__ __forceinline__ float row_score(
    const float* __restrict__ cand, const float* kps, const float* __restrict__ kinorm, int n)
{
    float acc0 = 0.f, acc1 = 0.f;
    #pragma unroll 4
    for (int d = 0; d < FDIM; d += 8) {
        float4 v0 = *(const float4*)(cand + (size_t)n*FDIM + d);
        float4 v1 = *(const float4*)(cand + (size_t)n*FDIM + d + 4);
        acc0 += v0.x*kps[d]   + v0.y*kps[d+1] + v0.z*kps[d+2] + v0.w*kps[d+3];
        acc1 += v1.x*kps[d+4] + v1.y*kps[d+5] + v1.z*kps[d+6] + v1.w*kps[d+7];
    }
    return kinorm[n] - 2.f*(acc0 + acc1);
}

// ---------- fixup (cold path) ----------
__global__ __launch_bounds__(256) void k_fix(
    const float* __restrict__ kp, const float* __restrict__ cand,
    const float* __restrict__ kinorm, int* __restrict__ cnt, int* __restrict__ candI)
{
    __shared__ float kps[FDIM];
    __shared__ unsigned h[1024];
    __shared__ unsigned pr[256];
    __shared__ unsigned h2[64];
    __shared__ int tstar;
    __shared__ unsigned cbel;
    __shared__ unsigned Tsh;
    int b = blockIdx.x, tid = threadIdx.x;
    int c0 = cnt[b*CSTR];
    if (c0 >= CTX && c0 <= CAP) return;
    if (tid < FDIM) kps[tid] = kp[(size_t)b*FDIM + tid];
    #pragma unroll
    for (int i = 0; i < 4; ++i) h[tid + i*256] = 0;
    if (tid == 0) tstar = 1023;
    if (tid < 64) h2[tid] = 0;
    __syncthreads();
    for (int n = tid; n < NTOT; n += 256) {
        float sc = fmaxf(row_score(cand, kps, kinorm, n), 0.f);
        _Float16 k16 = (_Float16)sc;
        unsigned short kb; __builtin_memcpy(&kb, &k16, 2);
        atomicAdd(&h[kb >> 6], 1u);
    }
    __syncthreads();
    unsigned s0 = h[tid*4], s1 = h[tid*4+1], s2 = h[tid*4+2], s3 = h[tid*4+3];
    unsigned tot = s0 + s1 + s2 + s3;
    pr[tid] = tot;
    __syncthreads();
    for (int off = 1; off < 256; off <<= 1) {
        unsigned t2 = (tid >= off) ? pr[tid - off] : 0;
        __syncthreads();
        pr[tid] += t2;
        __syncthreads();
    }
    unsigned c = pr[tid] - tot;
    int found = -1;
    c += s0; if (c >= CTX) found = tid*4;
    if (found < 0) { c += s1; if (c >= CTX) found = tid*4+1; }
    if (found < 0) { c += s2; if (c >= CTX) found = tid*4+2; }
    if (found < 0) { c += s3; if (c >= CTX) found = tid*4+3; }
    if (found >= 0) atomicMin(&tstar, found);
    __syncthreads();
    if (tid == (tstar >> 2)) {
        unsigned below = pr[tid] - tot;
        int pos = tstar & 3;
        if (pos > 0) below += s0;
        if (pos > 1) below += s1;
        if (pos > 2) below += s2;
        cbel = below;
    }
    __syncthreads();
    int ts = tstar;
    for (int n = tid; n < NTOT; n += 256) {
        float sc = fmaxf(row_score(cand, kps, kinorm, n), 0.f);
        _Float16 k16 = (_Float16)sc;
        unsigned short kb; __builtin_memcpy(&kb, &k16, 2);
        if ((int)((unsigned)kb >> 6) == ts) atomicAdd(&h2[kb & 63], 1u);
    }
    __syncthreads();
    if (tid == 0) {
        unsigned cum = cbel; int code = 63;
        for (int i = 0; i < 64; ++i) { cum += h2[i]; if (cum >= CTX) { code = i; break; } }
        Tsh = (unsigned)((ts << 6) + code);
        cnt[b*CSTR] = 0;
    }
    __syncthreads();
    unsigned T2 = Tsh;
    for (int n = tid; n < NTOT; n += 256) {
        float sc = fmaxf(row_score(cand, kps, kinorm, n), 0.f);
        _Float16 k16 = (_Float16)sc;
        unsigned short kb; __builtin_memcpy(&kb, &k16, 2);
        if ((unsigned)kb <= T2) {
            int pp = atomicAdd(&cnt[b*CSTR], 1);
            if (pp < CAP) candI[(size_t)b*CAP + pp] = n;
        }
    }
}

// ---------- exact fp32 rescore + top-96 + fused softmax weights ----------
__global__ __launch_bounds__(256) void k_resc(
    const float* __restrict__ kp, const float* __restrict__ cand,
    const float* __restrict__ kinorm, const int* __restrict__ cnt,
    const int* __restrict__ candI, const float* __restrict__ candy,
    int* __restrict__ finI, float* __restrict__ wts, float* __restrict__ wy)
{
    __shared__ float kps[FDIM];
    __shared__ float sval[2048];
    __shared__ int   sidx[2048];
    __shared__ float sh[256];
    int b = blockIdx.x, tid = threadIdx.x;
    if (tid < FDIM) kps[tid] = kp[(size_t)b*FDIM + tid];
    if (tid < 128) { sval[tid] = INFINITY; sidx[tid] = 0x7fffffff; }
    int nc = cnt[b*CSTR]; if (nc > CAP) nc = CAP;
    __syncthreads();
    for (int c0 = 0; c0 < nc; c0 += 1920) {
        int m = nc - c0; if (m > 1920) m = 1920;
        for (int c = tid; c < m; c += 256) {
            int n = candI[(size_t)b*CAP + c0 + c];
            sval[128 + c] = row_score(cand, kps, kinorm, n);
            sidx[128 + c] = n;
        }
        __syncthreads();
        int nv = 128 + m;
        int size = 256; while (size < nv) size <<= 1;
        for (int i2 = nv + tid; i2 < size; i2 += 256) { sval[i2] = INFINITY; sidx[i2] = 0x7fffffff; }
        __syncthreads();
        for (int k2 = 2; k2 <= size; k2 <<= 1) {
            for (int jj = k2 >> 1; jj > 0; jj >>= 1) {
                for (int i = tid; i < size; i += 256) {
                    int ix = i ^ jj;
                    if (ix > i) {
                        bool up = ((i & k2) == 0);
                        float a = sval[i], b2 = sval[ix];
                        int ia = sidx[i], ib = sidx[ix];
                        bool gt = (a > b2) || (a == b2 && ia > ib);
                        if (gt == up) {
                            sval[i] = b2; sval[ix] = a;
                            sidx[i] = ib; sidx[ix] = ia;
                        }
                    }
                }
                __syncthreads();
            }
        }
    }
    if (tid < CTX) finI[(size_t)b*CTX + tid] = sidx[tid];
    float m = sval[CTX-1];
    float e = (tid < CTX) ? expf(sval[tid] - m) : 0.f;
    sh[tid] = e;
    __syncthreads();
    for (int s2 = 128; s2 > 0; s2 >>= 1) { if (tid < s2) sh[tid] += sh[tid+s2]; __syncthreads(); }
    float sum = sh[0];
    __syncthreads();
    float w = e / sum;
    if (tid < CTX) wts[(size_t)b*CTX + tid] = w;
    sh[tid] = (tid < CTX) ? w * candy[sidx[tid]] : 0.f;
    __syncthreads();
    for (int s2 = 128; s2 > 0; s2 >>= 1) { if (tid < s2) sh[tid] += sh[tid+s2]; __syncthreads(); }
    if (tid == 0) wy[b] = sh[0];
}

// ---------- K6: direct gathered T-MLP; writes Hw as split-f16 A-pack ----------
__global__ __launch_bounds__(256) void k_tmlp2(
    const _Float16* __restrict__ c2, const _Float16* __restrict__ Wsp,
    const float* __restrict__ xP,
    const int* __restrict__ finI, const float* __restrict__ wts,
    _Float16* __restrict__ Hw2)
{
    __shared__ __align__(16) _Float16 As[768*8];
    __shared__ __align__(16) _Float16 Bs[1024*8];
    __shared__ int   idx[CTX];
    __shared__ float wsh[CTX];
    int b = blockIdx.x, ct = blockIdx.y;
    int tid = threadIdx.x;
    int lane = tid & 63, wv = tid >> 6;
    if (tid < CTX) { idx[tid] = finI[b*CTX + tid]; wsh[tid] = wts[b*CTX + tid]; }
    __syncthreads();
    f32x4 acc[6][2] = {};
    const _Float16* Wbase = Wsp + (size_t)(DDIM + ct*128) * 384;
    for (int kt = 0; kt < 2; ++kt) {
        #pragma unroll
        for (int w = 0; w < 3; ++w) {
            int s = (wv*3 + w)*64 + lane;
            int rl = s & 15, q = (s >> 4) & 3, kk2 = (s >> 6) & 1, ii = s >> 7;
            int grow = idx[ii*16 + rl];
            __builtin_amdgcn_global_load_lds(
                (const __attribute__((address_space(1))) void*)(c2 + (size_t)grow*384 + kt*64 + (kk2*4 + q)*8),
                (__attribute__((address_space(3))) void*)(As + (size_t)s*8), 16, 0, 0);
        }
        #pragma unroll
        for (int w = 0; w < 4; ++w) {
            int s = (wv*4 + w)*64 + lane;
            int rl = s & 15, q = (s >> 4) & 3, kk2 = (s >> 6) & 1, jj = s >> 7;
            __builtin_amdgcn_global_load_lds(
                (const __attribute__((address_space(1))) void*)(Wbase + (size_t)(jj*16 + rl)*384 + kt*64 + (kk2*4 + q)*8),
                (__attribute__((address_space(3))) void*)(Bs + (size_t)s*8), 16, 0, 0);
        }
        __syncthreads();
        #pragma unroll
        for (int kk = 0; kk < 2; ++kk) {
            f16x8 bfr[2];
            #pragma unroll
            for (int j = 0; j < 2; ++j)
                bfr[j] = *(const f16x8*)&Bs[(((wv*2 + j)*2 + kk)*64 + (lane>>4)*16 + (lane&15))*8];
            #pragma unroll
            for (int i = 0; i < 6; ++i) {
                f16x8 af = *(const f16x8*)&As[((i*2 + kk)*64 + (lane>>4)*16 + (lane&15))*8];
                #pragma unroll
                for (int j = 0; j < 2; ++j)
                    acc[i][j] = __builtin_amdgcn_mfma_f32_16x16x32_f16(af, bfr[j], acc[i][j], 0, 0, 0);
            }
        }
        __syncthreads();
    }
    #pragma unroll
    for (int j = 0; j < 2; ++j) {
        int col = ct*128 + wv*32 + j*16 + (lane & 15);
        float xv = xP[(size_t)b*DIDIM + col];
        float p = 0.f;
        #pragma unroll
        for (int i = 0; i < 6; ++i) {
            #pragma unroll
            for (int rg = 0; rg < 4; ++rg) {
                int row = i*16 + (lane>>4)*4 + rg;
                p += wsh[row] * fmaxf(xv - acc[i][j][rg], 0.f);
            }
        }
        p += __shfl_xor(p, 16, 64);
        p += __shfl_xor(p, 32, 64);
        if ((lane >> 4) == 0) {
            _Float16 h = (_Float16)p;
            float hf = (float)h;
            Hw2[(size_t)b*1536 + col]        = h;
            Hw2[(size_t)b*1536 + 512 + col]  = (_Float16)(hf * 0.015625f);
            Hw2[(size_t)b*1536 + 1024 + col] = (_Float16)((p - hf) * 64.f);
        }
    }
}

// ---------- block-sum helper ----------
__device__ __forceinline__ float bsum(float v, float* red, int j)
{
    red[j] = v; __syncthreads();
    if (j < 64) {
        float t = red[j] + red[j+64] + red[j+128] + red[j+192];
        #pragma unroll
        for (int o2 = 32; o2; o2 >>= 1) t += __shfl_xor(t, o2, 64);
        if (j == 0) red[0] = t;
    }
    __syncthreads();
    float t = red[0];
    __syncthreads();
    return t;
}

// ---------- G1: x = xenc + wy*WY + bY + Hw @ WT2  (MFMA, Kp=1536) ----------
__global__ __launch_bounds__(256) void k_g1(
    const _Float16* __restrict__ Hw2, const _Float16* __restrict__ Wfin,
    const float* __restrict__ xenc, const float* __restrict__ wy,
    const float* __restrict__ WY, const float* __restrict__ bY,
    float* __restrict__ xbuf)
{
    __shared__ __align__(16) _Float16 As[128*64];
    __shared__ __align__(16) _Float16 Bs[128*64];
    int tid = threadIdx.x;
    int lane = tid & 63, wv = tid >> 6;
    int wm = wv >> 1, wn = wv & 1;
    int bn = blockIdx.x * 128;
    int bm = blockIdx.y * 128;
    f32x4 acc[4][4] = {};
    const size_t baseA = (size_t)bm * 1536;
    const size_t baseB = (size_t)WT2OFF + (size_t)bn * 1536;
    for (int kt = 0; kt < 24; ++kt) {
        #pragma unroll
        for (int r = 0; r < 4; ++r) {
            int w = wv*4 + r;
            int s = w*64 + lane;
            int rl = s & 15, q = (s>>4)&3, kk2 = (s>>6)&1, ii = (s>>7)&3, wq = (s>>9)&1;
            size_t goff = (size_t)(wq*64 + ii*16 + rl)*1536 + kt*64 + (kk2*4 + q)*8;
            __builtin_amdgcn_global_load_lds(
                (const __attribute__((address_space(1))) void*)(Hw2 + baseA + goff),
                (__attribute__((address_space(3))) void*)(As + w*512), 16, 0, 0);
            __builtin_amdgcn_global_load_lds(
                (const __attribute__((address_space(1))) void*)(Wfin + baseB + goff),
                (__attribute__((address_space(3))) void*)(Bs + w*512), 16, 0, 0);
        }
        __syncthreads();
        #pragma unroll
        for (int kk = 0; kk < 2; ++kk) {
            f16x8 af[4], bfr[4];
            #pragma unroll
            for (int i = 0; i < 4; ++i)
                af[i] = *(const f16x8*)&As[((wm*8 + i*2 + kk)*64 + (lane>>4)*16 + (lane&15))*8];
            #pragma unroll
            for (int j = 0; j < 4; ++j)
                bfr[j] = *(const f16x8*)&Bs[((wn*8 + j*2 + kk)*64 + (lane>>4)*16 + (lane&15))*8];
            #pragma unroll
            for (int i = 0; i < 4; ++i)
                #pragma unroll
                for (int j = 0; j < 4; ++j)
                    acc[i][j] = __builtin_amdgcn_mfma_f32_16x16x32_f16(af[i], bfr[j], acc[i][j], 0, 0, 0);
        }
        __syncthreads();
    }
    #pragma unroll
    for (int i = 0; i < 4; ++i) {
        int m = bm + wm*64 + i*16 + (lane>>4)*4;
        #pragma unroll
        for (int j = 0; j < 4; ++j) {
            int n = bn + wn*64 + j*16 + (lane&15);
            #pragma unroll
            for (int rg = 0; rg < 4; ++rg) {
                int row = m + rg;
                float val = acc[i][j][rg] + xenc[(size_t)row*DDIM + n] + wy[row]*WY[n] + bY[n];
                xbuf[(size_t)row*DDIM + n] = val;
            }
        }
    }
}

// ---------- LN1: xs = LN(x)*lpg + lpb, written as split-f16 A-pack (Kp=768) ----------
__global__ __launch_bounds__(256) void k_ln1(
    const float* __restrict__ xbuf, const float* __restrict__ lpg,
    const float* __restrict__ lpb, _Float16* __restrict__ xs2)
{
    __shared__ float red[256];
    int b = blockIdx.x, j = threadIdx.x;
    float x = xbuf[(size_t)b*DDIM + j];
    float mean = bsum(x, red, j) * (1.f/DDIM);
    float xc = x - mean;
    float var = bsum(xc*xc, red, j) * (1.f/DDIM);
    float rstd = 1.f / sqrtf(var + 1e-5f);
    float v = xc * rstd * lpg[j] + lpb[j];
    _Float16 h = (_Float16)v;
    float hf = (float)h;
    xs2[(size_t)b*768 + j]       = h;
    xs2[(size_t)b*768 + 256 + j] = (_Float16)(hf * 0.015625f);
    xs2[(size_t)b*768 + 512 + j] = (_Float16)((v - hf) * 64.f);
}

// ---------- G2: U = relu(xs @ WP1 + bP1), written as split-f16 A-pack (Kp=768 in, 1536 out) ----------
__global__ __launch_bounds__(256) void k_g2(
    const _Float16* __restrict__ xs2, const _Float16* __restrict__ Wfin,
    const float* __restrict__ bP1, _Float16* __restrict__ U2)
{
    __shared__ __align__(16) _Float16 As[128*64];
    __shared__ __align__(16) _Float16 Bs[128*64];
    int tid = threadIdx.x;
    int lane = tid & 63, wv = tid >> 6;
    int wm = wv >> 1, wn = wv & 1;
    int bn = blockIdx.x * 128;
    int bm = blockIdx.y * 128;
    f32x4 acc[4][4] = {};
    const size_t baseA = (size_t)bm * 768;
    const size_t baseB = (size_t)WP1OFF + (size_t)bn * 768;
    for (int kt = 0; kt < 12; ++kt) {
        #pragma unroll
        for (int r = 0; r < 4; ++r) {
            int w = wv*4 + r;
            int s = w*64 + lane;
            int rl = s & 15, q = (s>>4)&3, kk2 = (s>>6)&1, ii = (s>>7)&3, wq = (s>>9)&1;
            size_t goff = (size_t)(wq*64 + ii*16 + rl)*768 + kt*64 + (kk2*4 + q)*8;
            __builtin_amdgcn_global_load_lds(
                (const __attribute__((address_space(1))) void*)(xs2 + baseA + goff),
                (__attribute__((address_space(3))) void*)(As + w*512), 16, 0, 0);
            __builtin_amdgcn_global_load_lds(
                (const __attribute__((address_space(1))) void*)(Wfin + baseB + goff),
                (__attribute__((address_space(3))) void*)(Bs + w*512), 16, 0, 0);
        }
        __syncthreads();
        #pragma unroll
        for (int kk = 0; kk < 2; ++kk) {
            f16x8 af[4], bfr[4];
            #pragma unroll
            for (int i = 0; i < 4; ++i)
                af[i] = *(const f16x8*)&As[((wm*8 + i*2 + kk)*64 + (lane>>4)*16 + (lane&15))*8];
            #pragma unroll
            for (int j = 0; j < 4; ++j)
                bfr[j] = *(const f16x8*)&Bs[((wn*8 + j*2 + kk)*64 + (lane>>4)*16 + (lane&15))*8];
            #pragma unroll
            for (int i = 0; i < 4; ++i)
                #pragma unroll
                for (int j = 0; j < 4; ++j)
                    acc[i][j] = __builtin_amdgcn_mfma_f32_16x16x32_f16(af[i], bfr[j], acc[i][j], 0, 0, 0);
        }
        __syncthreads();
    }
    #pragma unroll
    for (int i = 0; i < 4; ++i) {
        int m = bm + wm*64 + i*16 + (lane>>4)*4;
        #pragma unroll
        for (int j = 0; j < 4; ++j) {
            int n = bn + wn*64 + j*16 + (lane&15);
            float bv = bP1[n];
            #pragma unroll
            for (int rg = 0; rg < 4; ++rg) {
                int row = m + rg;
                float r = fmaxf(acc[i][j][rg] + bv, 0.f);
                _Float16 h = (_Float16)r;
                float hf = (float)h;
                U2[(size_t)row*1536 + n]        = h;
                U2[(size_t)row*1536 + 512 + n]  = (_Float16)(hf * 0.015625f);
                U2[(size_t)row*1536 + 1024 + n] = (_Float16)((r - hf) * 64.f);
            }
        }
    }
}

// ---------- G3: x2 = x + U @ WP2 + bP2  (MFMA, Kp=1536) ----------
__global__ __launch_bounds__(256) void k_g3(
    const _Float16* __restrict__ U2, const _Float16* __restrict__ Wfin,
    const float* __restrict__ xbuf, const float* __restrict__ bP2,
    float* __restrict__ x2buf)
{
    __shared__ __align__(16) _Float16 As[128*64];
    __shared__ __align__(16) _Float16 Bs[128*64];
    int tid = threadIdx.x;
    int lane = tid & 63, wv = tid >> 6;
    int wm = wv >> 1, wn = wv & 1;
    int bn = blockIdx.x * 128;
    int bm = blockIdx.y * 128;
    f32x4 acc[4][4] = {};
    const size_t baseA = (size_t)bm * 1536;
    const size_t baseB = (size_t)WP2OFF + (size_t)bn * 1536;
    for (int kt = 0; kt < 24; ++kt) {
        #pragma unroll
        for (int r = 0; r < 4; ++r) {
            int w = wv*4 + r;
            int s = w*64 + lane;
            int rl = s & 15, q = (s>>4)&3, kk2 = (s>>6)&1, ii = (s>>7)&3, wq = (s>>9)&1;
            size_t goff = (size_t)(wq*64 + ii*16 + rl)*1536 + kt*64 + (kk2*4 + q)*8;
            __builtin_amdgcn_global_load_lds(
                (const __attribute__((address_space(1))) void*)(U2 + baseA + goff),
                (__attribute__((address_space(3))) void*)(As + w*512), 16, 0, 0);
            __builtin_amdgcn_global_load_lds(
                (const __attribute__((address_space(1))) void*)(Wfin + baseB + goff),
                (__attribute__((address_space(3))) void*)(Bs + w*512), 16, 0, 0);
        }
        __syncthreads();
        #pragma unroll
        for (int kk = 0; kk < 2; ++kk) {
            f16x8 af[4], bfr[4];
            #pragma unroll
            for (int i = 0; i < 4; ++i)
                af[i] = *(const f16x8*)&As[((wm*8 + i*2 + kk)*64 + (lane>>4)*16 + (lane&15))*8];
            #pragma unroll
            for (int j = 0; j < 4; ++j)
                bfr[j] = *(const f16x8*)&Bs[((wn*8 + j*2 + kk)*64 + (lane>>4)*16 + (lane&15))*8];
            #pragma unroll
            for (int i = 0; i < 4; ++i)
                #pragma unroll
                for (int j = 0; j < 4; ++j)
                    acc[i][j] = __builtin_amdgcn_mfma_f32_16x16x32_f16(af[i], bfr[j], acc[i][j], 0, 0, 0);
        }
        __syncthreads();
    }
    #pragma unroll
    for (int i = 0; i < 4; ++i) {
        int m = bm + wm*64 + i*16 + (lane>>4)*4;
        #pragma unroll
        for (int j = 0; j < 4; ++j) {
            int n = bn + wn*64 + j*16 + (lane&15);
            float bv = bP2[n];
            #pragma unroll
            for (int rg = 0; rg < 4; ++rg) {
                int row = m + rg;
                x2buf[(size_t)row*DDIM + n] = acc[i][j][rg] + xbuf[(size_t)row*DDIM + n] + bv;
            }
        }
    }
}

// ---------- OUT: LN -> relu -> dot(Wout) + bout ----------
__global__ __launch_bounds__(256) void k_out(
    const float* __restrict__ x2buf, const float* __restrict__ logg,
    const float* __restrict__ lob, const float* __restrict__ Wout,
    const float* __restrict__ bout, float* __restrict__ out)
{
    __shared__ float red[256];
    int b = blockIdx.x, j = threadIdx.x;
    float x = x2buf[(size_t)b*DDIM + j];
    float mean = bsum(x, red, j) * (1.f/DDIM);
    float xc = x - mean;
    float var = bsum(xc*xc, red, j) * (1.f/DDIM);
    float rstd = 1.f / sqrtf(var + 1e-5f);
    float rr = fmaxf(xc * rstd * logg[j] + lob[j], 0.f);
    float s = bsum(rr * Wout[j], red, j);
    if (j == 0) out[b] = s + bout[0];
}

extern "C" void kernel_launch(void* const* d_in, const int* in_sizes, int n_in,
                              void* d_out, int out_size, void* d_ws, size_t ws_size,
                              hipStream_t stream)
{
    (void)in_sizes; (void)n_in; (void)out_size; (void)ws_size;
    const float* x_num = (const float*)d_in[0];
    const float* cand  = (const float*)d_in[1];
    const float* candy = (const float*)d_in[2];
    const float* Wlin  = (const float*)d_in[3];
    const float* blin  = (const float*)d_in[4];
    const float* WK    = (const float*)d_in[5];
    const float* bK    = (const float*)d_in[6];
    const float* WY    = (const float*)d_in[7];
    const float* bY    = (const float*)d_in[8];
    const float* WT1   = (const float*)d_in[9];
    const float* bT1   = (const float*)d_in[10];
    const float* WT2   = (const float*)d_in[11];
    const float* lpg   = (const float*)d_in[12];
    const float* lpb   = (const float*)d_in[13];
    const float* WP1   = (const float*)d_in[14];
    const float* bP1   = (const float*)d_in[15];
    const float* WP2   = (const float*)d_in[16];
    const float* bP2   = (const float*)d_in[17];
    const float* logg  = (const float*)d_in[18];
    const float* lob   = (const float*)d_in[19];
    const float* Wout  = (const float*)d_in[20];
    const float* bout  = (const float*)d_in[21];
    float* out = (float*)d_out;

    float* ws = (float*)d_ws;
    size_t o = 0;
    float* Wf     = ws + o; o += (size_t)FDIM*DDIM;
    float* bf     = ws + o; o += 320;
    float* WfT1   = ws + o; o += (size_t)FDIM*DIDIM;
    float* xenc   = ws + o; o += (size_t)BQ*DDIM;
    float* kp     = ws + o; o += (size_t)BQ*FDIM;
    float* kinorm = ws + o; o += NP;
    float* knp    = ws + o; o += (size_t)4*NP;
    int*   finI   = (int*)(ws + o); o += (size_t)BQ*CTX;
    float* wts    = ws + o; o += (size_t)BQ*CTX;
    float* wy     = ws + o; o += BQ;
    int*   Tq     = (int*)(ws + o); o += BQ;
    float* xP     = ws + o; o += (size_t)BQ*DIDIM;
    float* xbuf   = ws + o; o += (size_t)BQ*DDIM;
    float* x2buf  = ws + o; o += (size_t)BQ*DDIM;
    _Float16* kp2 = (_Float16*)(ws + o); o += (size_t)BQ*384/2;
    _Float16* c2  = (_Float16*)(ws + o); o += (size_t)NP*384/2;
    _Float16* Wsp = (_Float16*)(ws + o); o += (size_t)768*384/2;
    _Float16* Wfin= (_Float16*)(ws + o); o += (size_t)(WP2OFF + 256*1536)/2;
    _Float16* Hw2 = (_Float16*)(ws + o); o += (size_t)BQ*1536/2;
    _Float16* xs2 = (_Float16*)(ws + o); o += (size_t)BQ*768/2;
    _Float16* U2  = (_Float16*)(ws + o); o += (size_t)BQ*1536/2;
    int*   cnt    = (int*)(ws + o); o += (size_t)BQ*CSTR;
    int*   candI  = (int*)(ws + o); o += (size_t)BQ*CAP;
    _Float16* msb = (_Float16*)(ws + o); o += (size_t)BQ*MSUB;

    // prep: cand convert || Wf+WfT1 rows || bf || final-W packs
    k_prep<<<dim3(NCVT + FDIM + 1 + NPACK), dim3(256), 0, stream>>>(
        cand, c2, Wlin, blin, WK, bK, WT1, WT2, WP1, WP2, Wf, bf, WfT1, Wfin);
    // qenc || weight pack
    k_prep2<<<dim3(BQ + 384), dim3(256), 0, stream>>>(
        x_num, Wlin, blin, Wf, bf, WfT1, bT1, xenc, kp, kp2, xP, Wsp);

    // kinorm via split-f16 MFMA
    k_cnorm<<<dim3(DDIM/128, NP/128), dim3(256), 0, stream>>>(c2, Wsp, knp, bf);
    k_norm_fin<<<dim3(NP/256), dim3(256), 0, stream>>>(knp, bf, kinorm);

    // per-row exact-code threshold from subsample scores; also zeroes cnt
    k_mini<<<dim3(BQ/128, MSUB/128), dim3(256), 0, stream>>>(kp2, c2, kinorm, msb);
    k_subT<<<dim3(BQ), dim3(256), 0, stream>>>((const unsigned short*)msb, Tq, cnt);

    // stage-1 select + exact rescore (+fused softmax weights)
    k_dist_mfma<<<dim3((BQ/128)*(NP/128)), dim3(256), 0, stream>>>(kp2, c2, kinorm, Tq, cnt, candI);
    k_fix<<<dim3(BQ), dim3(256), 0, stream>>>(kp, cand, kinorm, cnt, candI);
    k_resc<<<dim3(BQ), dim3(256), 0, stream>>>(kp, cand, kinorm, cnt, candI, candy,
                                               finI, wts, wy);

    // direct gathered T-MLP (writes Hw2 split pack)
    k_tmlp2<<<dim3(BQ, 4), dim3(256), 0, stream>>>(c2, Wsp, xP, finI, wts, Hw2);

    // final MLP as MFMA chain
    k_g1<<<dim3(2, 8), dim3(256), 0, stream>>>(Hw2, Wfin, xenc, wy, WY, bY, xbuf);
    k_ln1<<<dim3(BQ), dim3(256), 0, stream>>>(xbuf, lpg, lpb, xs2);
    k_g2<<<dim3(4, 8), dim3(256), 0, stream>>>(xs2, Wfin, bP1, U2);
    k_g3<<<dim3(2, 8), dim3(256), 0, stream>>>(U2, Wfin, xbuf, bP2, x2buf);
    k_out<<<dim3(BQ), dim3(256), 0, stream>>>(x2buf, logg, lob, Wout, bout, out);
}

// Round 25
// 380.762 us; speedup vs baseline: 1.2025x; 1.2025x over previous
//
#include <hip/hip_runtime.h>
#include <math.h>

#define BQ 1024
#define FDIM 128
#define DDIM 256
#define DIDIM 512
#define NTOT 100000
#define NP 100096            // padded to multiple of 128
#define NCVT 12512           // cand-convert blocks (NP*32/256)
#define CTX 96
#define CAP 8192
#define MSUB 12288
#define RSUB 48
#define LBUF 1280            // per-block LDS survivor buffer (~150 sigma headroom)
#define CSTR 16              // cnt stride (1 cache line per row)

typedef _Float16 f16x8 __attribute__((ext_vector_type(8)));
typedef _Float16 f16x4 __attribute__((ext_vector_type(4)));
typedef float f32x4 __attribute__((ext_vector_type(4)));

// ---------- K0: fused prep: cand->split-f16 convert  ||  Wf/WfT1 rows  ||  bf ----------
__global__ __launch_bounds__(256) void k_prep(
    const float* __restrict__ cand, _Float16* __restrict__ c2,
    const float* __restrict__ Wlin, const float* __restrict__ blin,
    const float* __restrict__ WK, const float* __restrict__ bK,
    const float* __restrict__ WT1,
    float* __restrict__ Wf, float* __restrict__ bf, float* __restrict__ WfT1)
{
    int blk = blockIdx.x, tid = threadIdx.x;
    if (blk < NCVT) {
        int t = blk*256 + tid;
        int row = t >> 5;
        int c4 = (t & 31) * 4;
        float4 v = {0.f, 0.f, 0.f, 0.f};
        if (row < NTOT) v = *(const float4*)(cand + (size_t)row*FDIM + c4);
        float vv[4] = {v.x, v.y, v.z, v.w};
        f16x4 h, hs, l;
        #pragma unroll
        for (int q = 0; q < 4; ++q) {
            _Float16 hq = (_Float16)vv[q];
            float hf = (float)hq;
            h[q]  = hq;
            hs[q] = (_Float16)(hf * 0.015625f);
            l[q]  = (_Float16)((vv[q] - hf) * 64.f);
        }
        size_t b = (size_t)row*384 + c4;
        *(f16x4*)(c2 + b)       = h;
        *(f16x4*)(c2 + b + 128) = hs;
        *(f16x4*)(c2 + b + 256) = l;
        return;
    }
    int i = blk - NCVT;
    __shared__ float red[256];
    int j = tid;
    if (i < FDIM) {
        float acc = 0.f;
        for (int l = 0; l < DDIM; ++l) acc += Wlin[i*DDIM + l] * WK[l*DDIM + j];
        Wf[i*DDIM + j] = acc;
        red[j] = acc;
        __syncthreads();
        float a0 = 0.f, a1 = 0.f;
        for (int l = 0; l < DDIM; ++l) {
            float w = red[l];
            a0 += w * WT1[(size_t)l*DIDIM + j];
            a1 += w * WT1[(size_t)l*DIDIM + j + 256];
        }
        WfT1[(size_t)i*DIDIM + j] = a0;
        WfT1[(size_t)i*DIDIM + j + 256] = a1;
    } else {
        float acc = bK[j];
        for (int l = 0; l < DDIM; ++l) acc += blin[l] * WK[l*DDIM + j];
        bf[j] = acc;
        red[j] = acc*acc; __syncthreads();
        for (int s2 = 128; s2 > 0; s2 >>= 1) { if (j < s2) red[j] += red[j+s2]; __syncthreads(); }
        if (j == 0) bf[256] = red[0];
    }
}

// ---------- K1: qenc blocks || weight-pack blocks ----------
__global__ __launch_bounds__(256) void k_prep2(
    const float* __restrict__ x, const float* __restrict__ Wlin,
    const float* __restrict__ blin, const float* __restrict__ Wf,
    const float* __restrict__ bf, const float* __restrict__ WfT1,
    const float* __restrict__ bT1,
    float* __restrict__ xenc, float* __restrict__ kp,
    _Float16* __restrict__ kp2, float* __restrict__ xP,
    _Float16* __restrict__ Wsp)
{
    __shared__ float xs[FDIM];
    __shared__ float ks[DDIM];
    int blk = blockIdx.x, tid = threadIdx.x;
    if (blk >= BQ) {
        int jj = (blk - BQ)*2 + (tid >> 7);
        int l = tid & 127;
        float w = (jj < DDIM) ? Wf[l*DDIM + jj] : WfT1[(size_t)l*DIDIM + (jj - DDIM)];
        _Float16 h = (_Float16)w;
        float hf = (float)h;
        Wsp[(size_t)jj*384 + l]       = h;
        Wsp[(size_t)jj*384 + 128 + l] = (_Float16)((w - hf) * 64.f);
        Wsp[(size_t)jj*384 + 256 + l] = (_Float16)(hf * 0.015625f);
        return;
    }
    int b = blk, j = tid;
    if (j < FDIM) xs[j] = x[(size_t)b*FDIM + j];
    __syncthreads();
    float a0 = blin[j], a1 = bf[j];
    for (int l = 0; l < FDIM; ++l) {
        float xv = xs[l];
        a0 += xv * Wlin[l*DDIM + j];
        a1 += xv * Wf[l*DDIM + j];
    }
    xenc[(size_t)b*DDIM + j] = a0;
    ks[j] = a1;
    float p0 = bT1[j], p1 = bT1[j + 256];
    for (int l = 0; l < FDIM; ++l) {
        float xv = xs[l];
        p0 += xv * WfT1[(size_t)l*DIDIM + j];
        p1 += xv * WfT1[(size_t)l*DIDIM + j + 256];
    }
    xP[(size_t)b*DIDIM + j] = p0;
    xP[(size_t)b*DIDIM + j + 256] = p1;
    __syncthreads();
    if (j < FDIM) {
        float a = 0.f;
        for (int d = 0; d < DDIM; ++d) a += Wf[j*DDIM + d] * ks[d];
        kp[(size_t)b*FDIM + j] = a;
        _Float16 h = (_Float16)a;
        float hf = (float)h;
        kp2[(size_t)b*384 + j]       = h;
        kp2[(size_t)b*384 + 128 + j] = (_Float16)((a - hf) * 64.f);
        kp2[(size_t)b*384 + 256 + j] = (_Float16)(hf * 0.015625f);
    }
}

// ---------- kinorm GEMM (round-16 2D version, 32 KB LDS) ----------
__global__ __launch_bounds__(256) void k_cnorm(
    const _Float16* __restrict__ A, const _Float16* __restrict__ B,
    float* __restrict__ knp, const float* __restrict__ bf)
{
    __shared__ __align__(16) _Float16 As[128*64];
    __shared__ __align__(16) _Float16 Bs[128*64];
    int tid = threadIdx.x;
    int lane = tid & 63, wv = tid >> 6;
    int wm = wv >> 1, wn = wv & 1;
    int bn = blockIdx.x * 128;
    int bm = blockIdx.y * 128;
    f32x4 acc[4][4] = {};
    const size_t baseA = (size_t)bm * 384;
    const size_t baseB = (size_t)bn * 384;
    for (int kt = 0; kt < 6; ++kt) {
        #pragma unroll
        for (int r = 0; r < 4; ++r) {
            int w = wv*4 + r;
            int s = w*64 + lane;
            int rl = s & 15;
            int q  = (s >> 4) & 3;
            int kk2= (s >> 6) & 1;
            int ii = (s >> 7) & 3;
            int wq = (s >> 9) & 1;
            size_t goff = (size_t)(wq*64 + ii*16 + rl)*384 + kt*64 + (kk2*4 + q)*8;
            __builtin_amdgcn_global_load_lds(
                (const __attribute__((address_space(1))) void*)(A + baseA + goff),
                (__attribute__((address_space(3))) void*)(As + w*512), 16, 0, 0);
            __builtin_amdgcn_global_load_lds(
                (const __attribute__((address_space(1))) void*)(B + baseB + goff),
                (__attribute__((address_space(3))) void*)(Bs + w*512), 16, 0, 0);
        }
        __syncthreads();
        #pragma unroll
        for (int kk = 0; kk < 2; ++kk) {
            f16x8 af[4], bfr[4];
            #pragma unroll
            for (int i = 0; i < 4; ++i)
                af[i] = *(const f16x8*)&As[((wm*8 + i*2 + kk)*64 + (lane>>4)*16 + (lane&15))*8];
            #pragma unroll
            for (int j = 0; j < 4; ++j)
                bfr[j] = *(const f16x8*)&Bs[((wn*8 + j*2 + kk)*64 + (lane>>4)*16 + (lane&15))*8];
            #pragma unroll
            for (int i = 0; i < 4; ++i)
                #pragma unroll
                for (int j = 0; j < 4; ++j)
                    acc[i][j] = __builtin_amdgcn_mfma_f32_16x16x32_f16(af[i], bfr[j], acc[i][j], 0, 0, 0);
        }
        __syncthreads();
    }
    float bfv[4];
    #pragma unroll
    for (int j = 0; j < 4; ++j) bfv[j] = bf[bn + wn*64 + j*16 + (lane&15)];
    int bnt = bn >> 7;
    #pragma unroll
    for (int i = 0; i < 4; ++i) {
        #pragma unroll
        for (int rg = 0; rg < 4; ++rg) {
            float s = 0.f;
            #pragma unroll
            for (int j = 0; j < 4; ++j) {
                float q = acc[i][j][rg];
                s += q * (q + 2.f*bfv[j]);
            }
            s += __shfl_xor(s, 1, 64);
            s += __shfl_xor(s, 2, 64);
            s += __shfl_xor(s, 4, 64);
            s += __shfl_xor(s, 8, 64);
            if ((lane & 15) == 0) {
                int row = bm + wm*64 + i*16 + (lane>>4)*4 + rg;
                knp[(size_t)(bnt*2 + wn)*NP + row] = s;
            }
        }
    }
}

// ---------- finalize kinorm ----------
__global__ __launch_bounds__(256) void k_norm_fin(
    const float* __restrict__ knp, const float* __restrict__ bf, float* __restrict__ kinorm)
{
    int n = blockIdx.x*256 + threadIdx.x;
    kinorm[n] = (n < NTOT)
        ? bf[256] + knp[n] + knp[(size_t)NP + n] + knp[(size_t)2*NP + n] + knp[(size_t)3*NP + n]
        : INFINITY;
}

// ---------- mini score GEMM (K=128, hi-slot only) over first MSUB candidates ----------
__global__ __launch_bounds__(256) void k_mini(
    const _Float16* __restrict__ kp2, const _Float16* __restrict__ cand2,
    const float* __restrict__ kinorm, _Float16* __restrict__ msb)
{
    __shared__ __align__(16) _Float16 As[128*64];
    __shared__ __align__(16) _Float16 Bs[128*64];
    int tid = threadIdx.x;
    int lane = tid & 63, wv = tid >> 6;
    int wm = wv >> 1, wn = wv & 1;
    int bm = blockIdx.x * 128;
    int bn = blockIdx.y * 128;
    f32x4 acc[4][4] = {};
    const size_t baseA = (size_t)bm * 384;
    const size_t baseB = (size_t)bn * 384;
    for (int kt = 0; kt < 2; ++kt) {
        #pragma unroll
        for (int r = 0; r < 4; ++r) {
            int w = wv*4 + r;
            int s = w*64 + lane;
            int rl = s & 15;
            int q  = (s >> 4) & 3;
            int kk2= (s >> 6) & 1;
            int ii = (s >> 7) & 3;
            int wq = (s >> 9) & 1;
            size_t goff = (size_t)(wq*64 + ii*16 + rl)*384 + kt*64 + (kk2*4 + q)*8;
            __builtin_amdgcn_global_load_lds(
                (const __attribute__((address_space(1))) void*)(kp2 + baseA + goff),
                (__attribute__((address_space(3))) void*)(As + w*512), 16, 0, 0);
            __builtin_amdgcn_global_load_lds(
                (const __attribute__((address_space(1))) void*)(cand2 + baseB + goff),
                (__attribute__((address_space(3))) void*)(Bs + w*512), 16, 0, 0);
        }
        __syncthreads();
        #pragma unroll
        for (int kk = 0; kk < 2; ++kk) {
            f16x8 af[4], bfr[4];
            #pragma unroll
            for (int i = 0; i < 4; ++i)
                af[i] = *(const f16x8*)&As[((wm*8 + i*2 + kk)*64 + (lane>>4)*16 + (lane&15))*8];
            #pragma unroll
            for (int j = 0; j < 4; ++j)
                bfr[j] = *(const f16x8*)&Bs[((wn*8 + j*2 + kk)*64 + (lane>>4)*16 + (lane&15))*8];
            #pragma unroll
            for (int i = 0; i < 4; ++i)
                #pragma unroll
                for (int j = 0; j < 4; ++j)
                    acc[i][j] = __builtin_amdgcn_mfma_f32_16x16x32_f16(af[i], bfr[j], acc[i][j], 0, 0, 0);
        }
        __syncthreads();
    }
    #pragma unroll
    for (int i = 0; i < 4; ++i) {
        int m = bm + wm*64 + i*16 + (lane>>4)*4;
        #pragma unroll
        for (int j = 0; j < 4; ++j) {
            int nl = bn + wn*64 + j*16 + (lane&15);
            float kn = kinorm[nl];
            #pragma unroll
            for (int rg = 0; rg < 4; ++rg)
                msb[(size_t)(m + rg)*MSUB + nl] = (_Float16)fmaxf(kn - 2.f*acc[i][j][rg], 0.f);
        }
    }
}

// ---------- per-row subsample threshold + zero cnt ----------
__global__ __launch_bounds__(256) void k_subT(
    const unsigned short* __restrict__ msb, int* __restrict__ Tq, int* __restrict__ cnt)
{
    __shared__ unsigned h[1024];
    __shared__ unsigned pr[256];
    __shared__ unsigned h2[64];
    __shared__ int tstar;
    __shared__ unsigned cbel;
    int b = blockIdx.x, tid = threadIdx.x;
    if (tid == 0) cnt[b*CSTR] = 0;
    #pragma unroll
    for (int i = 0; i < 4; ++i) h[tid + i*256] = 0;
    if (tid == 0) tstar = 1023;
    if (tid < 64) h2[tid] = 0;
    __syncthreads();
    const unsigned short* row = msb + (size_t)b*MSUB;
    for (int base = 0; base < MSUB; base += 2048) {
        uint4 u = *(const uint4*)(row + base + tid*8);
        atomicAdd(&h[(u.x & 0xffffu) >> 6], 1u);
        atomicAdd(&h[(u.x >> 16) >> 6], 1u);
        atomicAdd(&h[(u.y & 0xffffu) >> 6], 1u);
        atomicAdd(&h[(u.y >> 16) >> 6], 1u);
        atomicAdd(&h[(u.z & 0xffffu) >> 6], 1u);
        atomicAdd(&h[(u.z >> 16) >> 6], 1u);
        atomicAdd(&h[(u.w & 0xffffu) >> 6], 1u);
        atomicAdd(&h[(u.w >> 16) >> 6], 1u);
    }
    __syncthreads();
    unsigned s0 = h[tid*4], s1 = h[tid*4+1], s2 = h[tid*4+2], s3 = h[tid*4+3];
    unsigned tot = s0 + s1 + s2 + s3;
    pr[tid] = tot;
    __syncthreads();
    for (int off = 1; off < 256; off <<= 1) {
        unsigned t2 = (tid >= off) ? pr[tid - off] : 0;
        __syncthreads();
        pr[tid] += t2;
        __syncthreads();
    }
    unsigned c = pr[tid] - tot;
    int found = -1;
    c += s0; if (c >= RSUB) found = tid*4;
    if (found < 0) { c += s1; if (c >= RSUB) found = tid*4+1; }
    if (found < 0) { c += s2; if (c >= RSUB) found = tid*4+2; }
    if (found < 0) { c += s3; if (c >= RSUB) found = tid*4+3; }
    if (found >= 0) atomicMin(&tstar, found);
    __syncthreads();
    if (tid == (tstar >> 2)) {
        unsigned below = pr[tid] - tot;
        int pos = tstar & 3;
        if (pos > 0) below += s0;
        if (pos > 1) below += s1;
        if (pos > 2) below += s2;
        cbel = below;
    }
    __syncthreads();
    int ts = tstar;
    for (int base = 0; base < MSUB; base += 2048) {
        uint4 u = *(const uint4*)(row + base + tid*8);
        unsigned e[8] = { u.x & 0xffffu, u.x >> 16, u.y & 0xffffu, u.y >> 16,
                          u.z & 0xffffu, u.z >> 16, u.w & 0xffffu, u.w >> 16 };
        #pragma unroll
        for (int q = 0; q < 8; ++q)
            if ((int)(e[q] >> 6) == ts) atomicAdd(&h2[e[q] & 63], 1u);
    }
    __syncthreads();
    if (tid == 0) {
        unsigned cum = cbel; int code = 63;
        for (int i = 0; i < 64; ++i) { cum += h2[i]; if (cum >= RSUB) { code = i; break; } }
        Tq[b] = (ts << 6) + code;
    }
}

// ---------- main score GEMM (LDS-staged kinorm/Tq epilogue) ----------
__global__ __launch_bounds__(256) void k_dist_mfma(
    const _Float16* __restrict__ kp2, const _Float16* __restrict__ cand2,
    const float* __restrict__ kinorm, const int* __restrict__ Tq,
    int* __restrict__ cnt, int* __restrict__ candI)
{
    __shared__ __align__(16) _Float16 As[128*64];
    __shared__ __align__(16) _Float16 Bs[128*64];
    __shared__ int lcnt;
    __shared__ unsigned lbuf[LBUF];
    __shared__ float kns[128];
    __shared__ int tqss[128];
    int tid = threadIdx.x;
    int lane = tid & 63, wv = tid >> 6;
    int wm = wv >> 1, wn = wv & 1;
    int r0 = blockIdx.x & 7, u0 = blockIdx.x >> 3;
    int pq = r0*782 + u0;
    int bm = (pq & 7) * 128;
    int bn = (pq >> 3) * 128;
    if (tid == 0) lcnt = 0;
    if (tid < 128) { kns[tid] = kinorm[bn + tid]; tqss[tid] = Tq[bm + tid]; }
    f32x4 acc[4][4] = {};
    const size_t baseA = (size_t)bm * 384;
    const size_t baseB = (size_t)bn * 384;
    for (int kt = 0; kt < 2; ++kt) {
        #pragma unroll
        for (int r = 0; r < 4; ++r) {
            int w = wv*4 + r;
            int s = w*64 + lane;
            int rl = s & 15;
            int q  = (s >> 4) & 3;
            int kk2= (s >> 6) & 1;
            int ii = (s >> 7) & 3;
            int wq = (s >> 9) & 1;
            size_t goff = (size_t)(wq*64 + ii*16 + rl)*384 + kt*64 + (kk2*4 + q)*8;
            __builtin_amdgcn_global_load_lds(
                (const __attribute__((address_space(1))) void*)(kp2 + baseA + goff),
                (__attribute__((address_space(3))) void*)(As + w*512), 16, 0, 0);
            __builtin_amdgcn_global_load_lds(
                (const __attribute__((address_space(1))) void*)(cand2 + baseB + goff),
                (__attribute__((address_space(3))) void*)(Bs + w*512), 16, 0, 0);
        }
        __syncthreads();
        #pragma unroll
        for (int kk = 0; kk < 2; ++kk) {
            f16x8 af[4], bfr[4];
            #pragma unroll
            for (int i = 0; i < 4; ++i)
                af[i] = *(const f16x8*)&As[((wm*8 + i*2 + kk)*64 + (lane>>4)*16 + (lane&15))*8];
            #pragma unroll
            for (int j = 0; j < 4; ++j)
                bfr[j] = *(const f16x8*)&Bs[((wn*8 + j*2 + kk)*64 + (lane>>4)*16 + (lane&15))*8];
            #pragma unroll
            for (int i = 0; i < 4; ++i)
                #pragma unroll
                for (int j = 0; j < 4; ++j)
                    acc[i][j] = __builtin_amdgcn_mfma_f32_16x16x32_f16(af[i], bfr[j], acc[i][j], 0, 0, 0);
        }
        __syncthreads();
    }
    #pragma unroll
    for (int i = 0; i < 4; ++i) {
        int m0 = bm + wm*64 + i*16 + (lane>>4)*4;
        int lrow = wm*64 + i*16 + (lane>>4)*4;
        int tqs[4];
        #pragma unroll
        for (int rg = 0; rg < 4; ++rg) tqs[rg] = tqss[lrow + rg];
        #pragma unroll
        for (int j = 0; j < 4; ++j) {
            int lcol = wn*64 + j*16 + (lane&15);
            int nl = bn + lcol;
            float kn = kns[lcol];
            #pragma unroll
            for (int rg = 0; rg < 4; ++rg) {
                float sc = fmaxf(kn - 2.f*acc[i][j][rg], 0.f);
                _Float16 k16 = (_Float16)sc;
                unsigned short kb;
                __builtin_memcpy(&kb, &k16, 2);
                if (kb <= (unsigned short)tqs[rg]) {
                    int p = atomicAdd(&lcnt, 1);
                    if (p < LBUF) lbuf[p] = ((unsigned)(m0 + rg) << 17) | (unsigned)nl;
                    else {
                        int pp = atomicAdd(&cnt[(m0 + rg)*CSTR], 1);
                        if (pp < CAP) candI[(size_t)(m0 + rg)*CAP + pp] = nl;
                    }
                }
            }
        }
    }
    __syncthreads();
    int c = lcnt < LBUF ? lcnt : LBUF;
    for (int i2 = tid; i2 < c; i2 += 256) {
        unsigned pk = lbuf[i2];
        int row = pk >> 17, col = (int)(pk & 0x1ffffu);
        int pp = atomicAdd(&cnt[row*CSTR], 1);
        if (pp < CAP) candI[(size_t)row*CAP + pp] = col;
    }
}

// ---------- fp32 row score helper ----------
__device__ __forceinline__ float row_score(
    const float* __restrict__ cand, const float* kps, const float* __restrict__ kinorm, int n)
{
    float acc0 = 0.f, acc1 = 0.f;
    #pragma unroll 4
    for (int d = 0; d < FDIM; d += 8) {
        float4 v0 = *(const float4*)(cand + (size_t)n*FDIM + d);
        float4 v1 = *(const float4*)(cand + (size_t)n*FDIM + d + 4);
        acc0 += v0.x*kps[d]   + v0.y*kps[d+1] + v0.z*kps[d+2] + v0.w*kps[d+3];
        acc1 += v1.x*kps[d+4] + v1.y*kps[d+5] + v1.z*kps[d+6] + v1.w*kps[d+7];
    }
    return kinorm[n] - 2.f*(acc0 + acc1);
}

// ---------- fixup (cold path) ----------
__global__ __launch_bounds__(256) void k_fix(
    const float* __restrict__ kp, const float* __restrict__ cand,
    const float* __restrict__ kinorm, int* __restrict__ cnt, int* __restrict__ candI)
{
    __shared__ float kps[FDIM];
    __shared__ unsigned h[1024];
    __shared__ unsigned pr[256];
    __shared__ unsigned h2[64];
    __shared__ int tstar;
    __shared__ unsigned cbel;
    __shared__ unsigned Tsh;
    int b = blockIdx.x, tid = threadIdx.x;
    int c0 = cnt[b*CSTR];
    if (c0 >= CTX && c0 <= CAP) return;
    if (tid < FDIM) kps[tid] = kp[(size_t)b*FDIM + tid];
    #pragma unroll
    for (int i = 0; i < 4; ++i) h[tid + i*256] = 0;
    if (tid == 0) tstar = 1023;
    if (tid < 64) h2[tid] = 0;
    __syncthreads();
    for (int n = tid; n < NTOT; n += 256) {
        float sc = fmaxf(row_score(cand, kps, kinorm, n), 0.f);
        _Float16 k16 = (_Float16)sc;
        unsigned short kb; __builtin_memcpy(&kb, &k16, 2);
        atomicAdd(&h[kb >> 6], 1u);
    }
    __syncthreads();
    unsigned s0 = h[tid*4], s1 = h[tid*4+1], s2 = h[tid*4+2], s3 = h[tid*4+3];
    unsigned tot = s0 + s1 + s2 + s3;
    pr[tid] = tot;
    __syncthreads();
    for (int off = 1; off < 256; off <<= 1) {
        unsigned t2 = (tid >= off) ? pr[tid - off] : 0;
        __syncthreads();
        pr[tid] += t2;
        __syncthreads();
    }
    unsigned c = pr[tid] - tot;
    int found = -1;
    c += s0; if (c >= CTX) found = tid*4;
    if (found < 0) { c += s1; if (c >= CTX) found = tid*4+1; }
    if (found < 0) { c += s2; if (c >= CTX) found = tid*4+2; }
    if (found < 0) { c += s3; if (c >= CTX) found = tid*4+3; }
    if (found >= 0) atomicMin(&tstar, found);
    __syncthreads();
    if (tid == (tstar >> 2)) {
        unsigned below = pr[tid] - tot;
        int pos = tstar & 3;
        if (pos > 0) below += s0;
        if (pos > 1) below += s1;
        if (pos > 2) below += s2;
        cbel = below;
    }
    __syncthreads();
    int ts = tstar;
    for (int n = tid; n < NTOT; n += 256) {
        float sc = fmaxf(row_score(cand, kps, kinorm, n), 0.f);
        _Float16 k16 = (_Float16)sc;
        unsigned short kb; __builtin_memcpy(&kb, &k16, 2);
        if ((int)((unsigned)kb >> 6) == ts) atomicAdd(&h2[kb & 63], 1u);
    }
    __syncthreads();
    if (tid == 0) {
        unsigned cum = cbel; int code = 63;
        for (int i = 0; i < 64; ++i) { cum += h2[i]; if (cum >= CTX) { code = i; break; } }
        Tsh = (unsigned)((ts << 6) + code);
        cnt[b*CSTR] = 0;
    }
    __syncthreads();
    unsigned T2 = Tsh;
    for (int n = tid; n < NTOT; n += 256) {
        float sc = fmaxf(row_score(cand, kps, kinorm, n), 0.f);
        _Float16 k16 = (_Float16)sc;
        unsigned short kb; __builtin_memcpy(&kb, &k16, 2);
        if ((unsigned)kb <= T2) {
            int pp = atomicAdd(&cnt[b*CSTR], 1);
            if (pp < CAP) candI[(size_t)b*CAP + pp] = n;
        }
    }
}

// ---------- exact fp32 rescore + top-96 + fused softmax weights ----------
__global__ __launch_bounds__(256) void k_resc(
    const float* __restrict__ kp, const float* __restrict__ cand,
    const float* __restrict__ kinorm, const int* __restrict__ cnt,
    const int* __restrict__ candI, const float* __restrict__ candy,
    int* __restrict__ finI, float* __restrict__ wts, float* __restrict__ wy)
{
    __shared__ float kps[FDIM];
    __shared__ float sval[2048];
    __shared__ int   sidx[2048];
    __shared__ float sh[256];
    int b = blockIdx.x, tid = threadIdx.x;
    if (tid < FDIM) kps[tid] = kp[(size_t)b*FDIM + tid];
    if (tid < 128) { sval[tid] = INFINITY; sidx[tid] = 0x7fffffff; }
    int nc = cnt[b*CSTR]; if (nc > CAP) nc = CAP;
    __syncthreads();
    for (int c0 = 0; c0 < nc; c0 += 1920) {
        int m = nc - c0; if (m > 1920) m = 1920;
        for (int c = tid; c < m; c += 256) {
            int n = candI[(size_t)b*CAP + c0 + c];
            sval[128 + c] = row_score(cand, kps, kinorm, n);
            sidx[128 + c] = n;
        }
        __syncthreads();
        int nv = 128 + m;
        int size = 256; while (size < nv) size <<= 1;
        for (int i2 = nv + tid; i2 < size; i2 += 256) { sval[i2] = INFINITY; sidx[i2] = 0x7fffffff; }
        __syncthreads();
        for (int k2 = 2; k2 <= size; k2 <<= 1) {
            for (int jj = k2 >> 1; jj > 0; jj >>= 1) {
                for (int i = tid; i < size; i += 256) {
                    int ix = i ^ jj;
                    if (ix > i) {
                        bool up = ((i & k2) == 0);
                        float a = sval[i], b2 = sval[ix];
                        int ia = sidx[i], ib = sidx[ix];
                        bool gt = (a > b2) || (a == b2 && ia > ib);
                        if (gt == up) {
                            sval[i] = b2; sval[ix] = a;
                            sidx[i] = ib; sidx[ix] = ia;
                        }
                    }
                }
                __syncthreads();
            }
        }
    }
    if (tid < CTX) finI[(size_t)b*CTX + tid] = sidx[tid];
    float m = sval[CTX-1];
    float e = (tid < CTX) ? expf(sval[tid] - m) : 0.f;
    sh[tid] = e;
    __syncthreads();
    for (int s2 = 128; s2 > 0; s2 >>= 1) { if (tid < s2) sh[tid] += sh[tid+s2]; __syncthreads(); }
    float sum = sh[0];
    __syncthreads();
    float w = e / sum;
    if (tid < CTX) wts[(size_t)b*CTX + tid] = w;
    sh[tid] = (tid < CTX) ? w * candy[sidx[tid]] : 0.f;
    __syncthreads();
    for (int s2 = 128; s2 > 0; s2 >>= 1) { if (tid < s2) sh[tid] += sh[tid+s2]; __syncthreads(); }
    if (tid == 0) wy[b] = sh[0];
}

// ---------- K6: direct gathered T-MLP ----------
__global__ __launch_bounds__(256) void k_tmlp2(
    const _Float16* __restrict__ c2, const _Float16* __restrict__ Wsp,
    const float* __restrict__ xP,
    const int* __restrict__ finI, const float* __restrict__ wts,
    float* __restrict__ Hw)
{
    __shared__ __align__(16) _Float16 As[768*8];
    __shared__ __align__(16) _Float16 Bs[1024*8];
    __shared__ int   idx[CTX];
    __shared__ float wsh[CTX];
    int b = blockIdx.x, ct = blockIdx.y;
    int tid = threadIdx.x;
    int lane = tid & 63, wv = tid >> 6;
    if (tid < CTX) { idx[tid] = finI[b*CTX + tid]; wsh[tid] = wts[b*CTX + tid]; }
    __syncthreads();
    f32x4 acc[6][2] = {};
    const _Float16* Wbase = Wsp + (size_t)(DDIM + ct*128) * 384;
    for (int kt = 0; kt < 2; ++kt) {
        #pragma unroll
        for (int w = 0; w < 3; ++w) {
            int s = (wv*3 + w)*64 + lane;
            int rl = s & 15, q = (s >> 4) & 3, kk2 = (s >> 6) & 1, ii = s >> 7;
            int grow = idx[ii*16 + rl];
            __builtin_amdgcn_global_load_lds(
                (const __attribute__((address_space(1))) void*)(c2 + (size_t)grow*384 + kt*64 + (kk2*4 + q)*8),
                (__attribute__((address_space(3))) void*)(As + (size_t)s*8), 16, 0, 0);
        }
        #pragma unroll
        for (int w = 0; w < 4; ++w) {
            int s = (wv*4 + w)*64 + lane;
            int rl = s & 15, q = (s >> 4) & 3, kk2 = (s >> 6) & 1, jj = s >> 7;
            __builtin_amdgcn_global_load_lds(
                (const __attribute__((address_space(1))) void*)(Wbase + (size_t)(jj*16 + rl)*384 + kt*64 + (kk2*4 + q)*8),
                (__attribute__((address_space(3))) void*)(Bs + (size_t)s*8), 16, 0, 0);
        }
        __syncthreads();
        #pragma unroll
        for (int kk = 0; kk < 2; ++kk) {
            f16x8 bfr[2];
            #pragma unroll
            for (int j = 0; j < 2; ++j)
                bfr[j] = *(const f16x8*)&Bs[(((wv*2 + j)*2 + kk)*64 + (lane>>4)*16 + (lane&15))*8];
            #pragma unroll
            for (int i = 0; i < 6; ++i) {
                f16x8 af = *(const f16x8*)&As[((i*2 + kk)*64 + (lane>>4)*16 + (lane&15))*8];
                #pragma unroll
                for (int j = 0; j < 2; ++j)
                    acc[i][j] = __builtin_amdgcn_mfma_f32_16x16x32_f16(af, bfr[j], acc[i][j], 0, 0, 0);
            }
        }
        __syncthreads();
    }
    #pragma unroll
    for (int j = 0; j < 2; ++j) {
        int col = ct*128 + wv*32 + j*16 + (lane & 15);
        float xv = xP[(size_t)b*DIDIM + col];
        float p = 0.f;
        #pragma unroll
        for (int i = 0; i < 6; ++i) {
            #pragma unroll
            for (int rg = 0; rg < 4; ++rg) {
                int row = i*16 + (lane>>4)*4 + rg;
                p += wsh[row] * fmaxf(xv - acc[i][j][rg], 0.f);
            }
        }
        p += __shfl_xor(p, 16, 64);
        p += __shfl_xor(p, 32, 64);
        if ((lane >> 4) == 0) Hw[(size_t)b*DIDIM + col] = p;
    }
}

// ---------- block-sum helper ----------
__device__ __forceinline__ float bsum(float v, float* red, int j)
{
    red[j] = v; __syncthreads();
    if (j < 64) {
        float t = red[j] + red[j+64] + red[j+128] + red[j+192];
        #pragma unroll
        for (int o2 = 32; o2; o2 >>= 1) t += __shfl_xor(t, o2, 64);
        if (j == 0) red[0] = t;
    }
    __syncthreads();
    float t = red[0];
    __syncthreads();
    return t;
}

// ---------- final: 2 rows/block, reg-batched loads + per-block K-tile phase offset ----------
__global__ __launch_bounds__(256, 2) void k_final2(
    const float* __restrict__ xenc, const float* __restrict__ Hw,
    const float* __restrict__ wy,
    const float* __restrict__ WY, const float* __restrict__ bY,
    const float* __restrict__ WT2,
    const float* __restrict__ lpg, const float* __restrict__ lpb,
    const float* __restrict__ WP1, const float* __restrict__ bP1,
    const float* __restrict__ WP2, const float* __restrict__ bP2,
    const float* __restrict__ logg, const float* __restrict__ lob,
    const float* __restrict__ Wout, const float* __restrict__ bout,
    float* __restrict__ out)
{
    __shared__ float hs[2][DIDIM];
    __shared__ float xs[2][DDIM];
    __shared__ float red[256];
    int b0 = blockIdx.x*2, j = threadIdx.x;
    // phase offset: de-synchronize weight-line demand across blocks (incl. co-resident pairs)
    int ph = ((int)blockIdx.x*5 + ((int)blockIdx.x >> 5)*9) & 31;
    #pragma unroll
    for (int r = 0; r < 2; ++r) {
        hs[r][j] = Hw[(size_t)(b0+r)*DIDIM + j];
        hs[r][j+256] = Hw[(size_t)(b0+r)*DIDIM + j + 256];
    }
    __syncthreads();
    // ---- GEMM1: v += hs . WT2[:, j]  (K=512, 32 tiles of 16; phase-rotated) ----
    float v0 = wy[b0]*WY[j] + bY[j];
    float v1 = wy[b0+1]*WY[j] + bY[j];
    for (int tt = 0; tt < 32; ++tt) {
        int t = (tt + ph) & 31;
        float w[16];
        #pragma unroll
        for (int q = 0; q < 16; ++q) w[q] = WT2[(size_t)(t*16+q)*DDIM + j];
        #pragma unroll
        for (int q = 0; q < 16; ++q) {
            v0 += hs[0][t*16+q]*w[q];
            v1 += hs[1][t*16+q]*w[q];
        }
    }
    float x[2];
    x[0] = xenc[(size_t)b0*DDIM + j] + v0;
    x[1] = xenc[(size_t)(b0+1)*DDIM + j] + v1;
    #pragma unroll
    for (int r = 0; r < 2; ++r) {
        float mean = bsum(x[r], red, j) * (1.f/DDIM);
        float xc = x[r] - mean;
        float var = bsum(xc*xc, red, j) * (1.f/DDIM);
        float rstd = 1.f / sqrtf(var + 1e-5f);
        xs[r][j] = xc * rstd * lpg[j] + lpb[j];
    }
    __syncthreads();
    // ---- GEMM2: u = xs . WP1 (K=256, 32 tiles of 8 dd x 2 cols; phase-rotated) ----
    float u00 = bP1[j], u01 = bP1[j+256];
    float u10 = bP1[j], u11 = bP1[j+256];
    for (int tt = 0; tt < 32; ++tt) {
        int t = (tt + ph) & 31;
        float w0[8], w1[8];
        #pragma unroll
        for (int q = 0; q < 8; ++q) {
            w0[q] = WP1[(size_t)(t*8+q)*DIDIM + j];
            w1[q] = WP1[(size_t)(t*8+q)*DIDIM + j + 256];
        }
        #pragma unroll
        for (int q = 0; q < 8; ++q) {
            float a0 = xs[0][t*8+q], a1 = xs[1][t*8+q];
            u00 += a0*w0[q]; u01 += a0*w1[q];
            u10 += a1*w0[q]; u11 += a1*w1[q];
        }
    }
    __syncthreads();
    hs[0][j] = fmaxf(u00, 0.f); hs[0][j+256] = fmaxf(u01, 0.f);
    hs[1][j] = fmaxf(u10, 0.f); hs[1][j+256] = fmaxf(u11, 0.f);
    __syncthreads();
    // ---- GEMM3: x2 += relu(h) . WP2 (K=512, 32 tiles of 16; phase-rotated) ----
    float x20 = x[0] + bP2[j];
    float x21 = x[1] + bP2[j];
    for (int tt = 0; tt < 32; ++tt) {
        int t = (tt + ph) & 31;
        float w[16];
        #pragma unroll
        for (int q = 0; q < 16; ++q) w[q] = WP2[(size_t)(t*16+q)*DDIM + j];
        #pragma unroll
        for (int q = 0; q < 16; ++q) {
            x20 += hs[0][t*16+q]*w[q];
            x21 += hs[1][t*16+q]*w[q];
        }
    }
    float x2[2] = {x20, x21};
    #pragma unroll
    for (int r = 0; r < 2; ++r) {
        float mean = bsum(x2[r], red, j) * (1.f/DDIM);
        float xc = x2[r] - mean;
        float var = bsum(xc*xc, red, j) * (1.f/DDIM);
        float rstd = 1.f / sqrtf(var + 1e-5f);
        float rr = fmaxf(xc * rstd * logg[j] + lob[j], 0.f);
        float s = bsum(rr * Wout[j], red, j);
        if (j == 0) out[b0+r] = s + bout[0];
    }
}

extern "C" void kernel_launch(void* const* d_in, const int* in_sizes, int n_in,
                              void* d_out, int out_size, void* d_ws, size_t ws_size,
                              hipStream_t stream)
{
    (void)in_sizes; (void)n_in; (void)out_size; (void)ws_size;
    const float* x_num = (const float*)d_in[0];
    const float* cand  = (const float*)d_in[1];
    const float* candy = (const float*)d_in[2];
    const float* Wlin  = (const float*)d_in[3];
    const float* blin  = (const float*)d_in[4];
    const float* WK    = (const float*)d_in[5];
    const float* bK    = (const float*)d_in[6];
    const float* WY    = (const float*)d_in[7];
    const float* bY    = (const float*)d_in[8];
    const float* WT1   = (const float*)d_in[9];
    const float* bT1   = (const float*)d_in[10];
    const float* WT2   = (const float*)d_in[11];
    const float* lpg   = (const float*)d_in[12];
    const float* lpb   = (const float*)d_in[13];
    const float* WP1   = (const float*)d_in[14];
    const float* bP1   = (const float*)d_in[15];
    const float* WP2   = (const float*)d_in[16];
    const float* bP2   = (const float*)d_in[17];
    const float* logg  = (const float*)d_in[18];
    const float* lob   = (const float*)d_in[19];
    const float* Wout  = (const float*)d_in[20];
    const float* bout  = (const float*)d_in[21];
    float* out = (float*)d_out;

    float* ws = (float*)d_ws;
    size_t o = 0;
    float* Wf     = ws + o; o += (size_t)FDIM*DDIM;
    float* bf     = ws + o; o += 320;
    float* WfT1   = ws + o; o += (size_t)FDIM*DIDIM;
    float* xenc   = ws + o; o += (size_t)BQ*DDIM;
    float* kp     = ws + o; o += (size_t)BQ*FDIM;
    float* kinorm = ws + o; o += NP;
    float* knp    = ws + o; o += (size_t)4*NP;
    int*   finI   = (int*)(ws + o); o += (size_t)BQ*CTX;
    float* wts    = ws + o; o += (size_t)BQ*CTX;
    float* wy     = ws + o; o += BQ;
    int*   Tq     = (int*)(ws + o); o += BQ;
    float* Hw     = ws + o; o += (size_t)BQ*DIDIM;
    float* xP     = ws + o; o += (size_t)BQ*DIDIM;
    _Float16* kp2 = (_Float16*)(ws + o); o += (size_t)BQ*384/2;
    _Float16* c2  = (_Float16*)(ws + o); o += (size_t)NP*384/2;
    _Float16* Wsp = (_Float16*)(ws + o); o += (size_t)768*384/2;
    int*   cnt    = (int*)(ws + o); o += (size_t)BQ*CSTR;
    int*   candI  = (int*)(ws + o); o += (size_t)BQ*CAP;
    _Float16* msb = (_Float16*)(ws + o); o += (size_t)BQ*MSUB;

    // prep: cand convert || Wf+WfT1 rows || bf
    k_prep<<<dim3(NCVT + FDIM + 1), dim3(256), 0, stream>>>(
        cand, c2, Wlin, blin, WK, bK, WT1, Wf, bf, WfT1);
    // qenc || weight pack
    k_prep2<<<dim3(BQ + 384), dim3(256), 0, stream>>>(
        x_num, Wlin, blin, Wf, bf, WfT1, bT1, xenc, kp, kp2, xP, Wsp);

    // kinorm via split-f16 MFMA
    k_cnorm<<<dim3(DDIM/128, NP/128), dim3(256), 0, stream>>>(c2, Wsp, knp, bf);
    k_norm_fin<<<dim3(NP/256), dim3(256), 0, stream>>>(knp, bf, kinorm);

    // per-row exact-code threshold from subsample scores; also zeroes cnt
    k_mini<<<dim3(BQ/128, MSUB/128), dim3(256), 0, stream>>>(kp2, c2, kinorm, msb);
    k_subT<<<dim3(BQ), dim3(256), 0, stream>>>((const unsigned short*)msb, Tq, cnt);

    // stage-1 select + exact rescore (+fused softmax weights)
    k_dist_mfma<<<dim3((BQ/128)*(NP/128)), dim3(256), 0, stream>>>(kp2, c2, kinorm, Tq, cnt, candI);
    k_fix<<<dim3(BQ), dim3(256), 0, stream>>>(kp, cand, kinorm, cnt, candI);
    k_resc<<<dim3(BQ), dim3(256), 0, stream>>>(kp, cand, kinorm, cnt, candI, candy,
                                               finI, wts, wy);

    // direct gathered T-MLP
    k_tmlp2<<<dim3(BQ, 4), dim3(256), 0, stream>>>(c2, Wsp, xP, finI, wts, Hw);
    k_final2<<<dim3(BQ/2), dim3(256), 0, stream>>>(xenc, Hw, wy, WY, bY, WT2,
                                                   lpg, lpb, WP1, bP1, WP2, bP2,
                                                   logg, lob, Wout, bout, out);
}